// Round 11
// baseline (2491.987 us; speedup 1.0000x reference)
//
#include <hip/hip_runtime.h>

#define TT 256
#define BB 4096
#define EPB 2   // batch elements per block

__device__ __forceinline__ float sigm(float x) {
  float e = __expf(-x);
  return __builtin_amdgcn_rcpf(1.0f + e);
}

__device__ __forceinline__ float tanhx(float x) {
  x = fminf(15.0f, fmaxf(-15.0f, x));
  float e = __expf(-2.0f * x);
  return (1.0f - e) * __builtin_amdgcn_rcpf(1.0f + e);
}

#define DOT4(acc, wv, xv)                 \
  do {                                    \
    acc = fmaf((wv).x, (xv).x, acc);      \
    acc = fmaf((wv).y, (xv).y, acc);      \
    acc = fmaf((wv).z, (xv).z, acc);      \
    acc = fmaf((wv).w, (xv).w, acc);      \
  } while (0)

// Block = 256 threads (4 waves), EPB=2. Wave w -> (dir = w>>1, kh = w&1).
// K-SPLIT design: each wave holds W_hh rows r/z/n restricted to h-columns
// [kh*32, kh*32+32) = 96 resident VGPRs (vs 192 in rounds 7/9, which pinned
// VGPR=252 -> hard 1 wave/SIMD -> 2030 us latency-exposed plateau).
// Per step the (dir,0)/(dir,1) wave pair each computes half-K partial dots for
// BOTH elements, exchanges 3 partials via LDS, and finishes elem=kh.
// LDS is PADDED to ~44 KB to pin 3 blocks/CU -> 12 waves/CU -> the allocator's
// occupancy-derived budget becomes 512/3 ~= 168 >= demand (~150) -> no spill
// (rounds 5-8: 34 KB -> 4 blocks -> 128-reg budget -> catastrophic W_hh spill).
// 3 waves/SIMD co-residency hides the scan's LDS/L1/transcendental latency
// that round 7 exposed (27% issue efficiency at 1 wave/SIMD).
__global__ __launch_bounds__(256) void gru_fused(
    const float* __restrict__ xin,    // [B][T][2]
    const float* __restrict__ wih1,   // [48][2]
    const float* __restrict__ whh1,   // [48][16]
    const float* __restrict__ bih1,   // [48]
    const float* __restrict__ bhh1,   // [48]
    const float* __restrict__ wihf,   // [192][16]
    const float* __restrict__ whhf,   // [192][64]
    const float* __restrict__ bihf,   // [192]
    const float* __restrict__ bhhf,   // [192]
    const float* __restrict__ wihb,
    const float* __restrict__ whhb,
    const float* __restrict__ bihb,
    const float* __restrict__ bhhb,
    const float* __restrict__ W1,     // [32][64]
    const float* __restrict__ b1,     // [32]
    const float* __restrict__ W2,     // [8][32]
    const float* __restrict__ b2,     // [8]
    float* __restrict__ zout)         // [B][8]
{
  __shared__ __align__(16) float out1L[EPB][TT][16];     // 32 KB layer-1 outputs
  __shared__ __align__(16) float parts[2][EPB][3][64];   // 6 KB cross-wave partials
  __shared__ __align__(16) float hs[2][EPB][64];         // [dir][elem][unit]
  __shared__ __align__(16) float hl1[EPB][16];           // layer-1 running h
  __shared__ __align__(16) float ys[EPB][32];            // MLP hidden
  __shared__ __align__(16) float lds_pad[1024];          // 4 KB: occupancy shaping
                                                         // total ~44.4 KB -> 3 blocks/CU

  const int tid = threadIdx.x;
  const int w   = tid >> 6;    // wave 0..3
  const int l   = tid & 63;
  const int dir = w >> 1;      // 0=fwd, 1=bwd
  const int kh  = w & 1;       // K-half of the hidden dot; also elem this wave finishes
  const int b0  = blockIdx.x * EPB;

  // keep lds_pad allocated (condition never true; compiler can't prove it)
  if (b0 > 0x0fffffff) { lds_pad[l] = 1.0f; zout[0] = lds_pad[l ^ 1]; }

  hs[dir][kh][l] = 0.0f;   // all 4 (dir,elem) slots zeroed before first barrier

  // ---------------- phase 1: layer-1 GRU; waves 0,1 do elem w ----------------
  if (w < 2 && l < 16) {
    const int u  = l;
    const int e1 = w;

    float wr[16], wz[16], wn[16];
#pragma unroll
    for (int j = 0; j < 16; ++j) {
      wr[j] = whh1[u * 16 + j];
      wz[j] = whh1[(16 + u) * 16 + j];
      wn[j] = whh1[(32 + u) * 16 + j];
    }
    const float wir0 = wih1[2 * u],        wir1 = wih1[2 * u + 1];
    const float wiz0 = wih1[2 * (16 + u)], wiz1 = wih1[2 * (16 + u) + 1];
    const float win0 = wih1[2 * (32 + u)], win1 = wih1[2 * (32 + u) + 1];
    const float br  = bih1[u] + bhh1[u];
    const float bz  = bih1[16 + u] + bhh1[16 + u];
    const float bin = bih1[32 + u];
    const float bhn = bhh1[32 + u];

    const float2* xp = (const float2*)xin + (size_t)(b0 + e1) * TT;

    float h1r = 0.0f;
    hl1[e1][u] = 0.0f;
    for (int t = 0; t < TT; ++t) {
      float2 xv = xp[t];
      float ar = fmaf(wir1, xv.y, fmaf(wir0, xv.x, br));
      float az = fmaf(wiz1, xv.y, fmaf(wiz0, xv.x, bz));
      float an = fmaf(win1, xv.y, fmaf(win0, xv.x, bin));
      float hr = 0.f, hz = 0.f, hn = bhn;
#pragma unroll
      for (int j = 0; j < 16; ++j) {
        float hj = hl1[e1][j];
        hr = fmaf(wr[j], hj, hr);
        hz = fmaf(wz[j], hj, hz);
        hn = fmaf(wn[j], hj, hn);
      }
      float r = sigm(ar + hr);
      float z = sigm(az + hz);
      float n = tanhx(fmaf(r, hn, an));
      h1r = fmaf(z, h1r - n, n);   // (1-z)*n + z*h
      hl1[e1][u] = h1r;
      out1L[e1][t][u] = h1r;
    }
  }
  __syncthreads();

  // ---------------- phase 2: K-split layer-2 scan ----------------
  const float* wih = dir ? wihb : wihf;
  const float* whh = dir ? whhb : whhf;
  const float* bih = dir ? bihb : bihf;
  const float* bhh = dir ? bhhb : bhhf;

  // W_hh rows l / 64+l / 128+l, columns [kh*32, kh*32+32): 96 fp32 resident.
  float4 wr2[8], wz2[8], wn2[8];
  {
    const float4* whh4 = (const float4*)whh;
#pragma unroll
    for (int j4 = 0; j4 < 8; ++j4) {
      wr2[j4] = whh4[l * 16 + kh * 8 + j4];
      wz2[j4] = whh4[(64 + l) * 16 + kh * 8 + j4];
      wn2[j4] = whh4[(128 + l) * 16 + kh * 8 + j4];
    }
  }
  const float bir = bih[l], biz = bih[64 + l], bin2 = bih[128 + l];
  const float bhr = bhh[l], bhz = bhh[64 + l], bhn2 = bhh[128 + l];

  float h = 0.0f;                          // running h of (dir, elem=kh), unit l
  const float4* wp = (const float4*)wih;   // laundered: stays an L1 stream

  for (int t2 = 0; t2 < TT / 2; ++t2) {
    // defeat LICM on the W_ih stream (hoisting 48 floats would blow the budget)
    asm volatile("" : "+v"(wp));
    const int ia = 2 * t2, ib = ia + 1;
    const int ta = dir ? (TT - 1 - ia) : ia;
    const int tb = dir ? (TT - 1 - ib) : ib;

    // x-projection for THIS wave's element (kh), steps A and B, full K=16
    float gxrA = bir, gxzA = biz, gxnA = bin2;
    float gxrB = bir, gxzB = biz, gxnB = bin2;
    {
      const float4* xa = (const float4*)&out1L[kh][ta][0];
      const float4* xb = (const float4*)&out1L[kh][tb][0];
#pragma unroll
      for (int i4 = 0; i4 < 4; ++i4) {
        const float4 wrv = wp[l * 4 + i4];
        const float4 wzv = wp[(64 + l) * 4 + i4];
        const float4 wnv = wp[(128 + l) * 4 + i4];
        const float4 va = xa[i4], vb = xb[i4];
        DOT4(gxrA, wrv, va); DOT4(gxzA, wzv, va); DOT4(gxnA, wnv, va);
        DOT4(gxrB, wrv, vb); DOT4(gxzB, wzv, vb); DOT4(gxnB, wnv, vb);
      }
    }

    // one GRU step: half-K partials for both elems -> exchange -> finish elem kh
#define SCAN_STEP(GXR, GXZ, GXN)                                               \
    {                                                                          \
      float pr0 = 0.f, pz0 = 0.f, pn0 = 0.f;                                   \
      float pr1 = 0.f, pz1 = 0.f, pn1 = 0.f;                                   \
      const float4* h0p = (const float4*)&hs[dir][0][kh * 32];                 \
      const float4* h1p = (const float4*)&hs[dir][1][kh * 32];                 \
      _Pragma("unroll")                                                        \
      for (int j4 = 0; j4 < 8; ++j4) {                                         \
        const float4 ha = h0p[j4], hb = h1p[j4];                               \
        DOT4(pr0, wr2[j4], ha); DOT4(pz0, wz2[j4], ha); DOT4(pn0, wn2[j4], ha);\
        DOT4(pr1, wr2[j4], hb); DOT4(pz1, wz2[j4], hb); DOT4(pn1, wn2[j4], hb);\
      }                                                                        \
      float opr, opz, opn;                                                     \
      if (kh == 0) {  /* finish elem 0; ship elem-1 partials */                \
        parts[dir][1][0][l] = pr1; parts[dir][1][1][l] = pz1;                  \
        parts[dir][1][2][l] = pn1;                                             \
        opr = pr0; opz = pz0; opn = pn0;                                       \
      } else {        /* finish elem 1; ship elem-0 partials */                \
        parts[dir][0][0][l] = pr0; parts[dir][0][1][l] = pz0;                  \
        parts[dir][0][2][l] = pn0;                                             \
        opr = pr1; opz = pz1; opn = pn1;                                       \
      }                                                                        \
      __syncthreads();                                                         \
      const float qr = parts[dir][kh][0][l];                                   \
      const float qz = parts[dir][kh][1][l];                                   \
      const float qn = parts[dir][kh][2][l];                                   \
      const float r = sigm((GXR) + opr + qr + bhr);                            \
      const float z = sigm((GXZ) + opz + qz + bhz);                            \
      const float n = tanhx(fmaf(r, opn + qn + bhn2, (GXN)));                  \
      h = fmaf(z, h - n, n);                                                   \
      hs[dir][kh][l] = h;                                                      \
      __syncthreads();                                                         \
    }

    SCAN_STEP(gxrA, gxzA, gxnA)
    SCAN_STEP(gxrB, gxzB, gxnB)
#undef SCAN_STEP
  }

  // ---------------- phase 3: h = h_fwd + h_bwd; MLP 64->32->8 (waves 0,1) ----
  if (w < 2 && l < 32) {
    const int s = l;
    float acc = b1[s];
    const float4* w1r = (const float4*)(W1 + s * 64);
#pragma unroll
    for (int j4 = 0; j4 < 16; ++j4) {
      const float4 hv0 = *(const float4*)&hs[0][w][j4 * 4];  // fwd, elem w
      const float4 hv1 = *(const float4*)&hs[1][w][j4 * 4];  // bwd, elem w
      const float4 wv  = w1r[j4];
      acc = fmaf(wv.x, hv0.x + hv1.x, acc);
      acc = fmaf(wv.y, hv0.y + hv1.y, acc);
      acc = fmaf(wv.z, hv0.z + hv1.z, acc);
      acc = fmaf(wv.w, hv0.w + hv1.w, acc);
    }
    ys[w][s] = acc;
  }
  // same-wave LDS write->read: in-order, no barrier needed
  if (w < 2 && l < 8) {
    float acc = b2[l];
#pragma unroll
    for (int j4 = 0; j4 < 8; ++j4) {
      const float4 yv = *(const float4*)&ys[w][j4 * 4];
      const float4 wv = *(const float4*)&W2[l * 32 + j4 * 4];
      DOT4(acc, wv, yv);
    }
    zout[(b0 + w) * 8 + l] = acc;
  }
}

extern "C" void kernel_launch(void* const* d_in, const int* in_sizes, int n_in,
                              void* d_out, int out_size, void* d_ws, size_t ws_size,
                              hipStream_t stream) {
  const float* all_traj = (const float*)d_in[0];
  const float* w_ih1  = (const float*)d_in[1];
  const float* w_hh1  = (const float*)d_in[2];
  const float* b_ih1  = (const float*)d_in[3];
  const float* b_hh1  = (const float*)d_in[4];
  const float* w_ih2f = (const float*)d_in[5];
  const float* w_hh2f = (const float*)d_in[6];
  const float* b_ih2f = (const float*)d_in[7];
  const float* b_hh2f = (const float*)d_in[8];
  const float* w_ih2b = (const float*)d_in[9];
  const float* w_hh2b = (const float*)d_in[10];
  const float* b_ih2b = (const float*)d_in[11];
  const float* b_hh2b = (const float*)d_in[12];
  const float* W1 = (const float*)d_in[13];
  const float* b1 = (const float*)d_in[14];
  const float* W2 = (const float*)d_in[15];
  const float* b2 = (const float*)d_in[16];
  float* z = (float*)d_out;

  // 2048 blocks x 256 threads (4 waves): wave = (direction, K-half/element)
  gru_fused<<<BB / EPB, 256, 0, stream>>>(
      all_traj, w_ih1, w_hh1, b_ih1, b_hh1,
      w_ih2f, w_hh2f, b_ih2f, b_hh2f,
      w_ih2b, w_hh2b, b_ih2b, b_hh2b,
      W1, b1, W2, b2, z);
}

// Round 12
// 2095.114 us; speedup vs baseline: 1.1894x; 1.1894x over previous
//
#include <hip/hip_runtime.h>

#define TT 256
#define BB 4096
#define EPB 4   // batch elements per block

__device__ __forceinline__ float sigm(float x) {
  float e = __expf(-x);
  return __builtin_amdgcn_rcpf(1.0f + e);
}

__device__ __forceinline__ float tanhx(float x) {
  x = fminf(15.0f, fmaxf(-15.0f, x));
  float e = __expf(-2.0f * x);
  return (1.0f - e) * __builtin_amdgcn_rcpf(1.0f + e);
}

// packed fp32 FMA: acc.lo += a.lo*b.lo, acc.hi += a.hi*b.hi (one VOP3P instr)
__device__ __forceinline__ void pkfma(float2& acc, float2 a, float2 b) {
  asm("v_pk_fma_f32 %0, %1, %2, %0" : "+v"(acc) : "v"(a), "v"(b));
}

// float4 viewed as two even-aligned float2 halves (no movs: .xy = v[a:a+1], .zw = v[a+2:a+3])
struct f2x2 { float2 lo, hi; };
__device__ __forceinline__ f2x2 split4(float4 q) {
  f2x2 r; r.lo = make_float2(q.x, q.y); r.hi = make_float2(q.z, q.w); return r;
}

#define PKDOT4(acc, wv, xv)            \
  do {                                 \
    pkfma(acc, (wv).lo, (xv).lo);      \
    pkfma(acc, (wv).hi, (xv).hi);      \
  } while (0)

#define DOT4(acc, wv, xv)                 \
  do {                                    \
    acc = fmaf((wv).x, (xv).x, acc);      \
    acc = fmaf((wv).y, (xv).y, acc);      \
    acc = fmaf((wv).z, (xv).z, acc);      \
    acc = fmaf((wv).w, (xv).w, acc);      \
  } while (0)

// ROUND-3 CHAMPION STRUCTURE (1455us, VALUBusy 75%, VGPR 200, no spill),
// with ONE change: phase-2 dot products use v_pk_fma_f32 (packed fp32, 2 FMA
// per instruction) -> dynamic FMA count per timestep 960 -> 480. The champion
// was issue-bound (75% VALU busy at 28% of fp32 peak); halving the instruction
// stream attacks that directly. Layout, residency policy (lb(128,1), compiler
// streams the over-budget weight slice from L1/L2), EPB=4 ILP, and sync
// structure are untouched.
// History: every occupancy/residency lever failed -- wpe(1,1)=1 wave/SIMD
// latency-exposed (2034); wpe(2,2)/(256-thr)=128-reg budget, W_hh spill (2436-
// 5500); K-split+barriers=lockstep overhead (2492). Round 3 remains the point
// to improve upon.
__global__ __launch_bounds__(128, 1) void gru_fused(
    const float* __restrict__ xin,    // [B][T][2]
    const float* __restrict__ wih1,   // [48][2]
    const float* __restrict__ whh1,   // [48][16]
    const float* __restrict__ bih1,   // [48]
    const float* __restrict__ bhh1,   // [48]
    const float* __restrict__ wihf,   // [192][16]
    const float* __restrict__ whhf,   // [192][64]
    const float* __restrict__ bihf,   // [192]
    const float* __restrict__ bhhf,   // [192]
    const float* __restrict__ wihb,
    const float* __restrict__ whhb,
    const float* __restrict__ bihb,
    const float* __restrict__ bhhb,
    const float* __restrict__ W1,     // [32][64]
    const float* __restrict__ b1,     // [32]
    const float* __restrict__ W2,     // [8][32]
    const float* __restrict__ b2,     // [8]
    float* __restrict__ zout)         // [B][8]
{
  __shared__ __align__(16) float out1L[EPB][TT][16];  // 64 KB layer-1 outputs
  __shared__ __align__(16) float hs[2][EPB][64];      // [dir][elem][unit]
  __shared__ __align__(16) float hl1[EPB][16];        // layer-1 running h
  __shared__ __align__(16) float ys[EPB][32];         // MLP hidden

  const int tid = threadIdx.x;
  const int w   = tid >> 6;   // wave: 0=fwd, 1=bwd
  const int l   = tid & 63;
  const int b0  = blockIdx.x * EPB;

  // ---------------- phase 1: layer-1 GRU, 2 elements per wave ----------------
  if (l < 32) {
    const int g = l >> 4;        // lane group within wave
    const int u = l & 15;        // hidden unit
    const int e = w * 2 + g;     // element 0..3

    float wr[16], wz[16], wn[16];
#pragma unroll
    for (int j = 0; j < 16; ++j) {
      wr[j] = whh1[u * 16 + j];
      wz[j] = whh1[(16 + u) * 16 + j];
      wn[j] = whh1[(32 + u) * 16 + j];
    }
    const float wir0 = wih1[2 * u],        wir1 = wih1[2 * u + 1];
    const float wiz0 = wih1[2 * (16 + u)], wiz1 = wih1[2 * (16 + u) + 1];
    const float win0 = wih1[2 * (32 + u)], win1 = wih1[2 * (32 + u) + 1];
    const float br  = bih1[u] + bhh1[u];
    const float bz  = bih1[16 + u] + bhh1[16 + u];
    const float bin = bih1[32 + u];
    const float bhn = bhh1[32 + u];

    const float2* xp = (const float2*)xin + (size_t)(b0 + e) * TT;

    float h = 0.0f;
    hl1[e][u] = 0.0f;
    for (int t = 0; t < TT; ++t) {
      float2 xv = xp[t];
      float ar = fmaf(wir1, xv.y, fmaf(wir0, xv.x, br));
      float az = fmaf(wiz1, xv.y, fmaf(wiz0, xv.x, bz));
      float an = fmaf(win1, xv.y, fmaf(win0, xv.x, bin));
      float hr = 0.f, hz = 0.f, hn = bhn;
#pragma unroll
      for (int j = 0; j < 16; ++j) {
        float hj = hl1[e][j];
        hr = fmaf(wr[j], hj, hr);
        hz = fmaf(wz[j], hj, hz);
        hn = fmaf(wn[j], hj, hn);
      }
      float r = sigm(ar + hr);
      float z = sigm(az + hz);
      float n = tanhx(fmaf(r, hn, an));
      h = fmaf(z, h - n, n);   // (1-z)*n + z*h
      hl1[e][u] = h;
      out1L[e][t][u] = h;
    }
  }
  __syncthreads();

  // ---------------- phase 2: layer-2 GRU (dir = w), lane l = unit l ----------------
  const float* wih = w ? wihb : wihf;
  const float* whh = w ? whhb : whhf;
  const float* bih = w ? bihb : bihf;
  const float* bhh = w ? bhhb : bhhf;

  // W_hh rows l / 64+l / 128+l as float2 half-pairs (192 fp32 wish; compiler
  // keeps what fits in the 200-reg budget and streams the rest from L1/L2,
  // exactly as in the 1455us champion).
  f2x2 wr2[16], wz2[16], wn2[16];
  {
    const float4* whh4 = (const float4*)whh;
#pragma unroll
    for (int j4 = 0; j4 < 16; ++j4) {
      wr2[j4] = split4(whh4[l * 16 + j4]);
      wz2[j4] = split4(whh4[(64 + l) * 16 + j4]);
      wn2[j4] = split4(whh4[(128 + l) * 16 + j4]);
    }
  }
  // W_ih rows: 48 fp32 wish.
  f2x2 wir2[4], wiz2[4], win2[4];
  {
    const float4* wih4 = (const float4*)wih;
#pragma unroll
    for (int i4 = 0; i4 < 4; ++i4) {
      wir2[i4] = split4(wih4[l * 4 + i4]);
      wiz2[i4] = split4(wih4[(64 + l) * 4 + i4]);
      win2[i4] = split4(wih4[(128 + l) * 4 + i4]);
    }
  }
  const float br2  = bih[l] + bhh[l];
  const float bz2  = bih[64 + l] + bhh[64 + l];
  const float bin2 = bih[128 + l];
  const float bhn2 = bhh[128 + l];

  float h0 = 0.f, h1 = 0.f, h2 = 0.f, h3 = 0.f;
  hs[w][0][l] = 0.f; hs[w][1][l] = 0.f; hs[w][2][l] = 0.f; hs[w][3][l] = 0.f;

#pragma unroll 1
  for (int t = 0; t < TT; ++t) {
    const int te = w ? (TT - 1 - t) : t;
    const float4* x0p = (const float4*)&out1L[0][te][0];
    const float4* x1p = (const float4*)&out1L[1][te][0];
    const float4* x2p = (const float4*)&out1L[2][te][0];
    const float4* x3p = (const float4*)&out1L[3][te][0];

    // input projection (packed): bias folded into acc.x; horizontal add at gate time
    float2 ar0 = make_float2(br2, 0.f), az0 = make_float2(bz2, 0.f), an0 = make_float2(bin2, 0.f);
    float2 ar1 = ar0, az1 = az0, an1 = an0;
    float2 ar2 = ar0, az2 = az0, an2 = an0;
    float2 ar3 = ar0, az3 = az0, an3 = an0;
#pragma unroll
    for (int i4 = 0; i4 < 4; ++i4) {
      const f2x2 wrv = wir2[i4], wzv = wiz2[i4], wnv = win2[i4];
      const f2x2 xa = split4(x0p[i4]);
      const f2x2 xb = split4(x1p[i4]);
      const f2x2 xc = split4(x2p[i4]);
      const f2x2 xd = split4(x3p[i4]);
      PKDOT4(ar0, wrv, xa); PKDOT4(az0, wzv, xa); PKDOT4(an0, wnv, xa);
      PKDOT4(ar1, wrv, xb); PKDOT4(az1, wzv, xb); PKDOT4(an1, wnv, xb);
      PKDOT4(ar2, wrv, xc); PKDOT4(az2, wzv, xc); PKDOT4(an2, wnv, xc);
      PKDOT4(ar3, wrv, xd); PKDOT4(az3, wzv, xd); PKDOT4(an3, wnv, xd);
    }

    // hidden projection (packed): h broadcast from LDS (uniform b128, conflict-free)
    float2 hr0 = make_float2(0.f, 0.f), hz0 = hr0, hn0 = make_float2(bhn2, 0.f);
    float2 hr1 = hr0, hz1 = hr0, hn1 = hn0;
    float2 hr2 = hr0, hz2 = hr0, hn2 = hn0;
    float2 hr3 = hr0, hz3 = hr0, hn3 = hn0;
#pragma unroll
    for (int j4 = 0; j4 < 16; ++j4) {
      const f2x2 ha = split4(*(const float4*)&hs[w][0][j4 * 4]);
      const f2x2 hb = split4(*(const float4*)&hs[w][1][j4 * 4]);
      const f2x2 hc = split4(*(const float4*)&hs[w][2][j4 * 4]);
      const f2x2 hd = split4(*(const float4*)&hs[w][3][j4 * 4]);
      const f2x2 wrv = wr2[j4], wzv = wz2[j4], wnv = wn2[j4];
      PKDOT4(hr0, wrv, ha); PKDOT4(hz0, wzv, ha); PKDOT4(hn0, wnv, ha);
      PKDOT4(hr1, wrv, hb); PKDOT4(hz1, wzv, hb); PKDOT4(hn1, wnv, hb);
      PKDOT4(hr2, wrv, hc); PKDOT4(hz2, wzv, hc); PKDOT4(hn2, wnv, hc);
      PKDOT4(hr3, wrv, hd); PKDOT4(hz3, wzv, hd); PKDOT4(hn3, wnv, hd);
    }

    { float r = sigm(ar0.x + ar0.y + hr0.x + hr0.y);
      float z = sigm(az0.x + az0.y + hz0.x + hz0.y);
      float n = tanhx(fmaf(r, hn0.x + hn0.y, an0.x + an0.y));
      h0 = fmaf(z, h0 - n, n); }
    { float r = sigm(ar1.x + ar1.y + hr1.x + hr1.y);
      float z = sigm(az1.x + az1.y + hz1.x + hz1.y);
      float n = tanhx(fmaf(r, hn1.x + hn1.y, an1.x + an1.y));
      h1 = fmaf(z, h1 - n, n); }
    { float r = sigm(ar2.x + ar2.y + hr2.x + hr2.y);
      float z = sigm(az2.x + az2.y + hz2.x + hz2.y);
      float n = tanhx(fmaf(r, hn2.x + hn2.y, an2.x + an2.y));
      h2 = fmaf(z, h2 - n, n); }
    { float r = sigm(ar3.x + ar3.y + hr3.x + hr3.y);
      float z = sigm(az3.x + az3.y + hz3.x + hz3.y);
      float n = tanhx(fmaf(r, hn3.x + hn3.y, an3.x + an3.y));
      h3 = fmaf(z, h3 - n, n); }

    hs[w][0][l] = h0; hs[w][1][l] = h1; hs[w][2][l] = h2; hs[w][3][l] = h3;
  }
  __syncthreads();

  // ---------------- phase 3: h = h_fwd + h_bwd; MLP 64->32->8 ----------------
  const int e3 = w * 2 + (l >> 5);   // element this half-wave finishes
  const int s  = l & 31;
  const int bo = b0 + e3;
  {
    float acc = b1[s];
    const float4* w1r = (const float4*)(W1 + s * 64);
#pragma unroll
    for (int j4 = 0; j4 < 16; ++j4) {
      const float4 hv0 = *(const float4*)&hs[0][e3][j4 * 4];
      const float4 hv1 = *(const float4*)&hs[1][e3][j4 * 4];
      const float4 wv  = w1r[j4];
      acc = fmaf(wv.x, hv0.x + hv1.x, acc);
      acc = fmaf(wv.y, hv0.y + hv1.y, acc);
      acc = fmaf(wv.z, hv0.z + hv1.z, acc);
      acc = fmaf(wv.w, hv0.w + hv1.w, acc);
    }
    ys[e3][s] = acc;
  }
  // same-wave LDS write->read: in-order, no barrier needed
  if (s < 8) {
    float acc = b2[s];
#pragma unroll
    for (int j4 = 0; j4 < 8; ++j4) {
      const float4 yv = *(const float4*)&ys[e3][j4 * 4];
      const float4 wv = *(const float4*)&W2[s * 32 + j4 * 4];
      DOT4(acc, wv, yv);
    }
    zout[bo * 8 + s] = acc;
  }
}

extern "C" void kernel_launch(void* const* d_in, const int* in_sizes, int n_in,
                              void* d_out, int out_size, void* d_ws, size_t ws_size,
                              hipStream_t stream) {
  const float* all_traj = (const float*)d_in[0];
  const float* w_ih1  = (const float*)d_in[1];
  const float* w_hh1  = (const float*)d_in[2];
  const float* b_ih1  = (const float*)d_in[3];
  const float* b_hh1  = (const float*)d_in[4];
  const float* w_ih2f = (const float*)d_in[5];
  const float* w_hh2f = (const float*)d_in[6];
  const float* b_ih2f = (const float*)d_in[7];
  const float* b_hh2f = (const float*)d_in[8];
  const float* w_ih2b = (const float*)d_in[9];
  const float* w_hh2b = (const float*)d_in[10];
  const float* b_ih2b = (const float*)d_in[11];
  const float* b_hh2b = (const float*)d_in[12];
  const float* W1 = (const float*)d_in[13];
  const float* b1 = (const float*)d_in[14];
  const float* W2 = (const float*)d_in[15];
  const float* b2 = (const float*)d_in[16];
  float* z = (float*)d_out;

  // 1024 blocks x 128 threads: each block = 4 batch elements, both dirs + MLP
  gru_fused<<<BB / EPB, 128, 0, stream>>>(
      all_traj, w_ih1, w_hh1, b_ih1, b_hh1,
      w_ih2f, w_hh2f, b_ih2f, b_hh2f,
      w_ih2b, w_hh2b, b_ih2b, b_hh2b,
      W1, b1, W2, b2, z);
}